// Round 7
// baseline (1287.591 us; speedup 1.0000x reference)
//
#include <hip/hip_runtime.h>
#include <hip/hip_bf16.h>
#include <stdint.h>

// MoE block: x[4,2048,1024] fp32, wg[1024,8], w0/w1[8,1024,4096], wo[8,4096,1024]
// fp32 gate -> top-2 -> per-expert token compaction (padded to BM) -> bf16 MFMA
// GEMM1 (dual acc: X@W0, X@W1, fused silu) -> H bf16 -> GEMM2 (H@Wo) -> weighted
// atomicAdd scatter into out (exactly 2 commutative fp32 adds per element).
// Workspace: 281 MB peak; wot aliases w0t (transpose-wo launched AFTER gemm1;
// stream-serial so no race).

#define T_TOK 8192
#define D_DIM 1024
#define F_DIM 4096
#define E_NUM 8
#define BM 128
#define BN 128
#define BK 32
#define MAXROWS 17408   // 2*T + E*BM padding
#define MAXTILES 136    // MAXROWS/BM

typedef __attribute__((ext_vector_type(8))) short bf16x8;
typedef __attribute__((ext_vector_type(4))) float f32x4;
typedef __attribute__((ext_vector_type(4))) unsigned int u32x4;

__device__ __forceinline__ unsigned short f2bf(float f) {
  union { float f; unsigned int u; } v; v.f = f;
  unsigned int r = v.u + 0x7FFFu + ((v.u >> 16) & 1u);  // RNE
  return (unsigned short)(r >> 16);
}

__device__ __forceinline__ void gl2lds16(const void* g, void* l) {
  __builtin_amdgcn_global_load_lds(
      (const __attribute__((address_space(1))) unsigned int*)g,
      (__attribute__((address_space(3))) unsigned int*)l, 16, 0, 0);
}

// ---------------- conversion kernels ----------------

__global__ __launch_bounds__(256) void cvt_x_kernel(const float* __restrict__ x,
                                                    unsigned short* __restrict__ xbf) {
  int i = blockIdx.x * blockDim.x + threadIdx.x;
  float4 v = ((const float4*)x)[i];
  ushort4 o;
  o.x = f2bf(v.x); o.y = f2bf(v.y); o.z = f2bf(v.z); o.w = f2bf(v.w);
  ((ushort4*)xbf)[i] = o;
}

// src: [E][R][C] fp32 -> dst: [E][C][R] bf16
__global__ __launch_bounds__(256) void transpose_cast_kernel(const float* __restrict__ src,
                                                             unsigned short* __restrict__ dst,
                                                             int R, int C) {
  __shared__ float tile[32][33];
  const float* s = src + (size_t)blockIdx.z * R * C;
  unsigned short* d = dst + (size_t)blockIdx.z * R * C;
  int c0 = blockIdx.x * 32, r0 = blockIdx.y * 32;
  int tx = threadIdx.x, ty = threadIdx.y;  // (32,8)
#pragma unroll
  for (int i = 0; i < 4; ++i)
    tile[ty + 8 * i][tx] = s[(size_t)(r0 + ty + 8 * i) * C + (c0 + tx)];
  __syncthreads();
#pragma unroll
  for (int i = 0; i < 4; ++i) {
    int cc = ty + 8 * i;
    d[(size_t)(c0 + cc) * R + (r0 + tx)] = f2bf(tile[tx][cc]);
  }
}

// ---------------- gate: fp32 logits, top-2, softmax, bucket scatter ----------------

__global__ __launch_bounds__(256) void gate_kernel(const float* __restrict__ x,
                                                   const float* __restrict__ wg,
                                                   int* __restrict__ counts,
                                                   int* __restrict__ btok,
                                                   float* __restrict__ bw) {
  int lane = threadIdx.x & 63;
  int t = blockIdx.x * 4 + (threadIdx.x >> 6);
  const float* xr = x + (size_t)t * D_DIM;
  float acc[8];
#pragma unroll
  for (int e = 0; e < 8; ++e) acc[e] = 0.f;
  for (int i = 0; i < D_DIM / 64; ++i) {
    int dd = i * 64 + lane;
    float xv = xr[dd];
    const float4 wa = *(const float4*)(wg + dd * 8);
    const float4 wb = *(const float4*)(wg + dd * 8 + 4);
    acc[0] += xv * wa.x; acc[1] += xv * wa.y; acc[2] += xv * wa.z; acc[3] += xv * wa.w;
    acc[4] += xv * wb.x; acc[5] += xv * wb.y; acc[6] += xv * wb.z; acc[7] += xv * wb.w;
  }
#pragma unroll
  for (int off = 32; off > 0; off >>= 1) {
#pragma unroll
    for (int e = 0; e < 8; ++e) acc[e] += __shfl_xor(acc[e], off);
  }
  if (lane == 0) {
    int b0 = 0; float v0 = acc[0];
#pragma unroll
    for (int e = 1; e < 8; ++e) if (acc[e] > v0) { v0 = acc[e]; b0 = e; }
    int b1 = -1; float v1 = -1e30f;
#pragma unroll
    for (int e = 0; e < 8; ++e) if (e != b0 && acc[e] > v1) { v1 = acc[e]; b1 = e; }
    float ew = __expf(v1 - v0);            // <= 1
    float rcp = 1.f / (1.f + ew);
    int p0 = atomicAdd(&counts[b0], 1);
    btok[b0 * T_TOK + p0] = t; bw[b0 * T_TOK + p0] = rcp;
    int p1 = atomicAdd(&counts[b1], 1);
    btok[b1 * T_TOK + p1] = t; bw[b1 * T_TOK + p1] = ew * rcp;
  }
}

// ---------------- routing compaction (single block) ----------------

__global__ __launch_bounds__(256) void route_kernel(const int* __restrict__ counts,
                                                    const int* __restrict__ btok,
                                                    const float* __restrict__ bw,
                                                    int* __restrict__ ctok,
                                                    float* __restrict__ cw,
                                                    int* __restrict__ texp) {
  __shared__ int st[9];
  __shared__ int cnt[8];
  if (threadIdx.x == 0) {
    int s = 0;
    for (int e = 0; e < 8; ++e) {
      cnt[e] = counts[e];
      st[e] = s;
      s += (cnt[e] + BM - 1) / BM * BM;   // pad each expert range to BM
    }
    st[8] = s;
  }
  __syncthreads();
  int total = st[8];
  for (int s = threadIdx.x; s < MAXROWS; s += blockDim.x) {
    int tok = -1; float w = 0.f;
    if (s < total) {
      int e = 0;
      while (e < 7 && s >= st[e + 1]) ++e;
      int i = s - st[e];
      if (i < cnt[e]) { tok = btok[e * T_TOK + i]; w = bw[e * T_TOK + i]; }
    }
    ctok[s] = tok; cw[s] = w;
  }
  for (int tile = threadIdx.x; tile < MAXTILES; tile += blockDim.x) {
    int s = tile * BM;
    int e = -1;
    if (s < total) { e = 0; while (e < 7 && s >= st[e + 1]) ++e; }
    texp[tile] = e;
  }
}

// ---------------- GEMM1: S0 = X@W0, S1 = X@W1, H = silu(S0)*S1 ----------------
// grid: (F/BN, MAXTILES); block 256 = 4 waves, each wave a 64x64 quadrant.

__global__ __launch_bounds__(256, 2) void moe_gemm1_kernel(
    const unsigned short* __restrict__ xbf,
    const unsigned short* __restrict__ w0t,   // [E][F][D] bf16
    const unsigned short* __restrict__ w1t,   // [E][F][D] bf16
    const int* __restrict__ ctok,
    const int* __restrict__ texp,
    unsigned short* __restrict__ H) {
  int tileR = blockIdx.y;
  int e = texp[tileR];
  if (e < 0) return;
  int fc = blockIdx.x * BN;
  int tid = threadIdx.x;
  int lane = tid & 63;
  int wave = tid >> 6;

  __shared__ __align__(16) unsigned char smem[32768];
  unsigned short (*sA)[BK]  = (unsigned short (*)[BK])(smem);          // [128][32]
  unsigned short (*sB0)[BK] = (unsigned short (*)[BK])(smem + 8192);
  unsigned short (*sB1)[BK] = (unsigned short (*)[BK])(smem + 16384);
  unsigned short (*sH)[BN]  = (unsigned short (*)[BN])(smem);          // reused post-loop

  // staging: 16B chunks c = tid and tid+256; row = c>>2, k-part = (c&3)*8
  int c0 = tid, c1 = tid + 256;
  int r0c = c0 >> 2, r1c = c1 >> 2;
  int t0 = ctok[tileR * BM + r0c]; if (t0 < 0) t0 = 0;   // pad rows read row 0 (finite garbage)
  int t1 = ctok[tileR * BM + r1c]; if (t1 < 0) t1 = 0;
  const unsigned short* gA0  = xbf + (size_t)t0 * D_DIM + (c0 & 3) * 8;
  const unsigned short* gA1  = xbf + (size_t)t1 * D_DIM + (c1 & 3) * 8;
  const unsigned short* gB00 = w0t + ((size_t)e * F_DIM + fc + r0c) * D_DIM + (c0 & 3) * 8;
  const unsigned short* gB01 = w0t + ((size_t)e * F_DIM + fc + r1c) * D_DIM + (c1 & 3) * 8;
  const unsigned short* gB10 = w1t + ((size_t)e * F_DIM + fc + r0c) * D_DIM + (c0 & 3) * 8;
  const unsigned short* gB11 = w1t + ((size_t)e * F_DIM + fc + r1c) * D_DIM + (c1 & 3) * 8;
  unsigned char* lA0  = smem + c0 * 16;
  unsigned char* lA1  = smem + c1 * 16;
  unsigned char* lB00 = smem + 8192 + c0 * 16;
  unsigned char* lB01 = smem + 8192 + c1 * 16;
  unsigned char* lB10 = smem + 16384 + c0 * 16;
  unsigned char* lB11 = smem + 16384 + c1 * 16;

  f32x4 zero = {0.f, 0.f, 0.f, 0.f};
  f32x4 acc0[4][4], acc1[4][4];
#pragma unroll
  for (int mi = 0; mi < 4; ++mi)
#pragma unroll
    for (int ni = 0; ni < 4; ++ni) { acc0[mi][ni] = zero; acc1[mi][ni] = zero; }

  int r15 = lane & 15, kg8 = (lane >> 4) * 8;
  int row0 = (wave >> 1) * 64, col0 = (wave & 1) * 64;

  for (int kt = 0; kt < D_DIM / BK; ++kt) {
    size_t ko = (size_t)kt * BK;
    gl2lds16(gA0 + ko, lA0);
    gl2lds16(gA1 + ko, lA1);
    gl2lds16(gB00 + ko, lB00);
    gl2lds16(gB01 + ko, lB01);
    gl2lds16(gB10 + ko, lB10);
    gl2lds16(gB11 + ko, lB11);
    __syncthreads();   // drains vmcnt before barrier
    bf16x8 bf0[4], bf1[4];
#pragma unroll
    for (int ni = 0; ni < 4; ++ni) {
      bf0[ni] = *(const bf16x8*)&sB0[col0 + ni * 16 + r15][kg8];
      bf1[ni] = *(const bf16x8*)&sB1[col0 + ni * 16 + r15][kg8];
    }
#pragma unroll
    for (int mi = 0; mi < 4; ++mi) {
      bf16x8 a = *(const bf16x8*)&sA[row0 + mi * 16 + r15][kg8];
#pragma unroll
      for (int ni = 0; ni < 4; ++ni) {
        acc0[mi][ni] = __builtin_amdgcn_mfma_f32_16x16x32_bf16(a, bf0[ni], acc0[mi][ni], 0, 0, 0);
        acc1[mi][ni] = __builtin_amdgcn_mfma_f32_16x16x32_bf16(a, bf1[ni], acc1[mi][ni], 0, 0, 0);
      }
    }
    __syncthreads();
  }

  // epilogue: h = silu(s0)*s1 -> LDS transpose -> coalesced 16B stores
  int kg4 = (lane >> 4) * 4;
#pragma unroll
  for (int mi = 0; mi < 4; ++mi) {
#pragma unroll
    for (int ni = 0; ni < 4; ++ni) {
      f32x4 s0 = acc0[mi][ni], s1 = acc1[mi][ni];
#pragma unroll
      for (int j = 0; j < 4; ++j) {
        float v = s0[j];
        float h = v / (1.f + __expf(-v)) * s1[j];
        sH[row0 + mi * 16 + kg4 + j][col0 + ni * 16 + r15] = f2bf(h);
      }
    }
  }
  __syncthreads();
  {
    int r = tid >> 1;
    const unsigned short* sp = &sH[r][(tid & 1) * 64];
    unsigned short* hp = H + ((size_t)tileR * BM + r) * F_DIM + fc + (tid & 1) * 64;
#pragma unroll
    for (int cch = 0; cch < 8; ++cch)
      ((u32x4*)hp)[cch] = ((const u32x4*)sp)[cch];
  }
}

// ---------------- GEMM2: out[tok] += w * (H @ Wo) ----------------
// grid: (D/BN, MAXTILES)

__global__ __launch_bounds__(256, 2) void moe_gemm2_kernel(
    const unsigned short* __restrict__ H,
    const unsigned short* __restrict__ wot,   // [E][D][F] bf16
    const int* __restrict__ ctok,
    const float* __restrict__ cw,
    const int* __restrict__ texp,
    float* __restrict__ out) {
  int tileR = blockIdx.y;
  int e = texp[tileR];
  if (e < 0) return;
  int dc = blockIdx.x * BN;
  int tid = threadIdx.x, lane = tid & 63, wave = tid >> 6;

  __shared__ __align__(16) unsigned char smem[16384];
  unsigned short (*sA)[BK] = (unsigned short (*)[BK])(smem);
  unsigned short (*sB)[BK] = (unsigned short (*)[BK])(smem + 8192);
  __shared__ int stok[BM];
  __shared__ float sw[BM];
  if (tid < BM) { stok[tid] = ctok[tileR * BM + tid]; sw[tid] = cw[tileR * BM + tid]; }

  int c0 = tid, c1 = tid + 256;
  int r0c = c0 >> 2, r1c = c1 >> 2;
  const unsigned short* gA0 = H + ((size_t)tileR * BM + r0c) * F_DIM + (c0 & 3) * 8;
  const unsigned short* gA1 = H + ((size_t)tileR * BM + r1c) * F_DIM + (c1 & 3) * 8;
  const unsigned short* gB0 = wot + ((size_t)e * D_DIM + dc + r0c) * F_DIM + (c0 & 3) * 8;
  const unsigned short* gB1 = wot + ((size_t)e * D_DIM + dc + r1c) * F_DIM + (c1 & 3) * 8;
  unsigned char* lA0 = smem + c0 * 16;
  unsigned char* lA1 = smem + c1 * 16;
  unsigned char* lB0 = smem + 8192 + c0 * 16;
  unsigned char* lB1 = smem + 8192 + c1 * 16;

  f32x4 zero = {0.f, 0.f, 0.f, 0.f};
  f32x4 acc[4][4];
#pragma unroll
  for (int mi = 0; mi < 4; ++mi)
#pragma unroll
    for (int ni = 0; ni < 4; ++ni) acc[mi][ni] = zero;

  int r15 = lane & 15, kg8 = (lane >> 4) * 8, kg4 = (lane >> 4) * 4;
  int row0 = (wave >> 1) * 64, col0 = (wave & 1) * 64;

  for (int kt = 0; kt < F_DIM / BK; ++kt) {
    size_t ko = (size_t)kt * BK;
    gl2lds16(gA0 + ko, lA0);
    gl2lds16(gA1 + ko, lA1);
    gl2lds16(gB0 + ko, lB0);
    gl2lds16(gB1 + ko, lB1);
    __syncthreads();
    bf16x8 bfr[4];
#pragma unroll
    for (int ni = 0; ni < 4; ++ni) bfr[ni] = *(const bf16x8*)&sB[col0 + ni * 16 + r15][kg8];
#pragma unroll
    for (int mi = 0; mi < 4; ++mi) {
      bf16x8 a = *(const bf16x8*)&sA[row0 + mi * 16 + r15][kg8];
#pragma unroll
      for (int ni = 0; ni < 4; ++ni)
        acc[mi][ni] = __builtin_amdgcn_mfma_f32_16x16x32_bf16(a, bfr[ni], acc[mi][ni], 0, 0, 0);
    }
    __syncthreads();
  }

#pragma unroll
  for (int mi = 0; mi < 4; ++mi) {
#pragma unroll
    for (int ni = 0; ni < 4; ++ni) {
#pragma unroll
      for (int j = 0; j < 4; ++j) {
        int r = row0 + mi * 16 + kg4 + j;
        int tok = stok[r];
        if (tok >= 0) {
          float val = acc[mi][ni][j] * sw[r];
          atomicAdd(&out[(size_t)tok * D_DIM + dc + col0 + ni * 16 + r15], val);
        }
      }
    }
  }
}

// ---------------- launch ----------------

extern "C" void kernel_launch(void* const* d_in, const int* in_sizes, int n_in,
                              void* d_out, int out_size, void* d_ws, size_t ws_size,
                              hipStream_t stream) {
  const float* x  = (const float*)d_in[0];
  const float* wg = (const float*)d_in[1];
  const float* w0 = (const float*)d_in[2];
  const float* w1 = (const float*)d_in[3];
  const float* wo = (const float*)d_in[4];
  float* out = (float*)d_out;

  char* ws = (char*)d_ws;
  size_t o = 0;
  auto carve = [&](size_t bytes) {
    char* p = ws + o;
    o = (o + bytes + 255) & ~(size_t)255;
    return p;
  };
  unsigned short* xbf  = (unsigned short*)carve((size_t)T_TOK * D_DIM * 2);         // 16 MB
  unsigned short* w0t  = (unsigned short*)carve((size_t)E_NUM * F_DIM * D_DIM * 2); // 64 MB
  unsigned short* w1t  = (unsigned short*)carve((size_t)E_NUM * F_DIM * D_DIM * 2); // 64 MB
  unsigned short* Hbuf = (unsigned short*)carve((size_t)MAXROWS * F_DIM * 2);       // 136 MB
  int*   counts = (int*)carve(8 * 4);
  int*   btok   = (int*)carve((size_t)E_NUM * T_TOK * 4);
  float* bwts   = (float*)carve((size_t)E_NUM * T_TOK * 4);
  int*   ctok   = (int*)carve((size_t)MAXROWS * 4);
  float* cwts   = (float*)carve((size_t)MAXROWS * 4);
  int*   texp   = (int*)carve((size_t)MAXTILES * 4);
  // wot ALIASES w0t: transpose-wo is launched after gemm1 (stream-serial), when
  // w0t is dead. Peak workspace = 281 MB instead of 345 MB.
  unsigned short* wot = w0t;
  (void)ws_size; (void)in_sizes; (void)n_in; (void)out_size;

  (void)hipMemsetAsync(d_out, 0, (size_t)T_TOK * D_DIM * 4, stream);
  (void)hipMemsetAsync(counts, 0, 8 * 4, stream);

  cvt_x_kernel<<<T_TOK * D_DIM / 4 / 256, 256, 0, stream>>>(x, xbf);
  dim3 tb(32, 8);
  transpose_cast_kernel<<<dim3(F_DIM / 32, D_DIM / 32, E_NUM), tb, 0, stream>>>(w0, w0t, D_DIM, F_DIM);
  transpose_cast_kernel<<<dim3(F_DIM / 32, D_DIM / 32, E_NUM), tb, 0, stream>>>(w1, w1t, D_DIM, F_DIM);
  gate_kernel<<<T_TOK / 4, 256, 0, stream>>>(x, wg, counts, btok, bwts);
  route_kernel<<<1, 256, 0, stream>>>(counts, btok, bwts, ctok, cwts, texp);
  moe_gemm1_kernel<<<dim3(F_DIM / BN, MAXTILES), 256, 0, stream>>>(xbf, w0t, w1t, ctok, texp, Hbuf);
  // wo transpose AFTER gemm1 so it can reuse w0t's memory
  transpose_cast_kernel<<<dim3(D_DIM / 32, F_DIM / 32, E_NUM), tb, 0, stream>>>(wo, wot, F_DIM, D_DIM);
  moe_gemm2_kernel<<<dim3(D_DIM / BN, MAXTILES), 256, 0, stream>>>(Hbuf, wot, ctok, cwts, texp, out);
}

// Round 9
// 1218.034 us; speedup vs baseline: 1.0571x; 1.0571x over previous
//
#include <hip/hip_runtime.h>
#include <hip/hip_bf16.h>
#include <stdint.h>

// MoE block: x[4,2048,1024] fp32, wg[1024,8], w0/w1[8,1024,4096], wo[8,4096,1024]
// R7: passed 1287us. R8 changes: BK=64 + XOR-swizzled LDS (T2, stage-source +
// read both swizzled, LDS dest linear) in both GEMMs; padded sH epilogue;
// transpose rewritten with 16B stores. Workspace stays 281MB (wot aliases w0t).

#define T_TOK 8192
#define D_DIM 1024
#define F_DIM 4096
#define E_NUM 8
#define BM 128
#define BN 128
#define BK 64
#define MAXROWS 17408   // 2*T + E*BM padding
#define MAXTILES 136    // MAXROWS/BM
#define SHP 136         // padded sH stride (ushorts), 272B row = 16B aligned

typedef __attribute__((ext_vector_type(8))) short bf16x8;
typedef __attribute__((ext_vector_type(4))) float f32x4;
typedef __attribute__((ext_vector_type(4))) unsigned int u32x4;

__device__ __forceinline__ unsigned short f2bf(float f) {
  union { float f; unsigned int u; } v; v.f = f;
  unsigned int r = v.u + 0x7FFFu + ((v.u >> 16) & 1u);  // RNE
  return (unsigned short)(r >> 16);
}

__device__ __forceinline__ void gl2lds16(const void* g, void* l) {
  __builtin_amdgcn_global_load_lds(
      (const __attribute__((address_space(1))) unsigned int*)g,
      (__attribute__((address_space(3))) unsigned int*)l, 16, 0, 0);
}

// ---------------- conversion kernels ----------------

__global__ __launch_bounds__(256) void cvt_x_kernel(const float* __restrict__ x,
                                                    unsigned short* __restrict__ xbf) {
  int i = blockIdx.x * blockDim.x + threadIdx.x;
  float4 v = ((const float4*)x)[i];
  ushort4 o;
  o.x = f2bf(v.x); o.y = f2bf(v.y); o.z = f2bf(v.z); o.w = f2bf(v.w);
  ((ushort4*)xbf)[i] = o;
}

// src: [E][R][C] fp32 -> dst: [E][C][R] bf16.
// Tile 128 src-rows x 64 src-cols; swizzled LDS; 16B output stores.
// grid (C/64, R/128, E), block 256.
__global__ __launch_bounds__(256) void transpose_cast_kernel(const float* __restrict__ src,
                                                             unsigned short* __restrict__ dst,
                                                             int R, int C) {
  __shared__ __align__(16) unsigned short lds[64 * 128];  // [dcol][swizzled srow] 16KB
  const float* s = src + (size_t)blockIdx.z * R * C;
  unsigned short* d = dst + (size_t)blockIdx.z * R * C;
  int c0 = blockIdx.x * 64, r0 = blockIdx.y * 128;
  int tid = threadIdx.x;
#pragma unroll
  for (int i = 0; i < 8; ++i) {
    int idx = tid + 256 * i;
    int row = idx >> 4, c4 = idx & 15;
    float4 v = *(const float4*)&s[(size_t)(r0 + row) * C + c0 + c4 * 4];
    float vv[4] = {v.x, v.y, v.z, v.w};
#pragma unroll
    for (int cc = 0; cc < 4; ++cc) {
      int dcol = c4 * 4 + cc;
      lds[dcol * 128 + (((row >> 3) ^ (dcol & 15)) << 3) + (row & 7)] = f2bf(vv[cc]);
    }
  }
  __syncthreads();
#pragma unroll
  for (int i = 0; i < 4; ++i) {
    int slot = tid + 256 * i;
    int drow = slot >> 4, q = slot & 15;
    u32x4 val = *(const u32x4*)&lds[drow * 128 + ((q ^ (drow & 15)) << 3)];
    *(u32x4*)&d[(size_t)(c0 + drow) * R + r0 + q * 8] = val;
  }
}

// ---------------- gate: fp32 logits, top-2, softmax, bucket scatter ----------------

__global__ __launch_bounds__(256) void gate_kernel(const float* __restrict__ x,
                                                   const float* __restrict__ wg,
                                                   int* __restrict__ counts,
                                                   int* __restrict__ btok,
                                                   float* __restrict__ bw) {
  int lane = threadIdx.x & 63;
  int t = blockIdx.x * 4 + (threadIdx.x >> 6);
  const float* xr = x + (size_t)t * D_DIM;
  float acc[8];
#pragma unroll
  for (int e = 0; e < 8; ++e) acc[e] = 0.f;
  for (int i = 0; i < D_DIM / 64; ++i) {
    int dd = i * 64 + lane;
    float xv = xr[dd];
    const float4 wa = *(const float4*)(wg + dd * 8);
    const float4 wb = *(const float4*)(wg + dd * 8 + 4);
    acc[0] += xv * wa.x; acc[1] += xv * wa.y; acc[2] += xv * wa.z; acc[3] += xv * wa.w;
    acc[4] += xv * wb.x; acc[5] += xv * wb.y; acc[6] += xv * wb.z; acc[7] += xv * wb.w;
  }
#pragma unroll
  for (int off = 32; off > 0; off >>= 1) {
#pragma unroll
    for (int e = 0; e < 8; ++e) acc[e] += __shfl_xor(acc[e], off);
  }
  if (lane == 0) {
    int b0 = 0; float v0 = acc[0];
#pragma unroll
    for (int e = 1; e < 8; ++e) if (acc[e] > v0) { v0 = acc[e]; b0 = e; }
    int b1 = -1; float v1 = -1e30f;
#pragma unroll
    for (int e = 0; e < 8; ++e) if (e != b0 && acc[e] > v1) { v1 = acc[e]; b1 = e; }
    float ew = __expf(v1 - v0);            // <= 1
    float rcp = 1.f / (1.f + ew);
    int p0 = atomicAdd(&counts[b0], 1);
    btok[b0 * T_TOK + p0] = t; bw[b0 * T_TOK + p0] = rcp;
    int p1 = atomicAdd(&counts[b1], 1);
    btok[b1 * T_TOK + p1] = t; bw[b1 * T_TOK + p1] = ew * rcp;
  }
}

// ---------------- routing compaction (single block) ----------------

__global__ __launch_bounds__(256) void route_kernel(const int* __restrict__ counts,
                                                    const int* __restrict__ btok,
                                                    const float* __restrict__ bw,
                                                    int* __restrict__ ctok,
                                                    float* __restrict__ cw,
                                                    int* __restrict__ texp) {
  __shared__ int st[9];
  __shared__ int cnt[8];
  if (threadIdx.x == 0) {
    int s = 0;
    for (int e = 0; e < 8; ++e) {
      cnt[e] = counts[e];
      st[e] = s;
      s += (cnt[e] + BM - 1) / BM * BM;
    }
    st[8] = s;
  }
  __syncthreads();
  int total = st[8];
  for (int s = threadIdx.x; s < MAXROWS; s += blockDim.x) {
    int tok = -1; float w = 0.f;
    if (s < total) {
      int e = 0;
      while (e < 7 && s >= st[e + 1]) ++e;
      int i = s - st[e];
      if (i < cnt[e]) { tok = btok[e * T_TOK + i]; w = bw[e * T_TOK + i]; }
    }
    ctok[s] = tok; cw[s] = w;
  }
  for (int tile = threadIdx.x; tile < MAXTILES; tile += blockDim.x) {
    int s = tile * BM;
    int e = -1;
    if (s < total) { e = 0; while (e < 7 && s >= st[e + 1]) ++e; }
    texp[tile] = e;
  }
}

// ---------------- GEMM1: S0 = X@W0, S1 = X@W1, H = silu(S0)*S1 ----------------
// BK=64, XOR-swizzled LDS rows (chunk c of row r holds logical chunk c^(r&7);
// achieved by permuting the GLOBAL source address; LDS dest linear for gl2lds).

__global__ __launch_bounds__(256, 2) void moe_gemm1_kernel(
    const unsigned short* __restrict__ xbf,
    const unsigned short* __restrict__ w0t,   // [E][F][D] bf16
    const unsigned short* __restrict__ w1t,   // [E][F][D] bf16
    const int* __restrict__ ctok,
    const int* __restrict__ texp,
    unsigned short* __restrict__ H) {
  int tileR = blockIdx.y;
  int e = texp[tileR];
  if (e < 0) return;
  int fc = blockIdx.x * BN;
  int tid = threadIdx.x;
  int lane = tid & 63;
  int wave = tid >> 6;

  __shared__ __align__(16) unsigned char smem[49152];  // A 16K | B0 16K | B1 16K
  unsigned short* sA  = (unsigned short*)(smem);
  unsigned short* sB0 = (unsigned short*)(smem + 16384);
  unsigned short* sB1 = (unsigned short*)(smem + 16384 * 2);
  unsigned short* sH  = (unsigned short*)(smem);       // reused post-loop [128][SHP]

  // staging: each thread owns chunks c = tid + 256*j (j=0..3) in each matrix.
  // row = c>>3, phys chunk pc = c&7 -> logical chunk lc = pc ^ (row&7).
  int rj[4], lcj[4];
#pragma unroll
  for (int j = 0; j < 4; ++j) {
    int c = tid + 256 * j;
    rj[j] = c >> 3;
    lcj[j] = (c & 7) ^ (rj[j] & 7);
  }
  const unsigned short* gA[4];
  const unsigned short* gB0[4];
  const unsigned short* gB1[4];
#pragma unroll
  for (int j = 0; j < 4; ++j) {
    int t0 = ctok[tileR * BM + rj[j]]; if (t0 < 0) t0 = 0;  // pad rows read row 0
    gA[j]  = xbf + (size_t)t0 * D_DIM + lcj[j] * 8;
    gB0[j] = w0t + ((size_t)e * F_DIM + fc + rj[j]) * D_DIM + lcj[j] * 8;
    gB1[j] = w1t + ((size_t)e * F_DIM + fc + rj[j]) * D_DIM + lcj[j] * 8;
  }

  f32x4 zero = {0.f, 0.f, 0.f, 0.f};
  f32x4 acc0[4][4], acc1[4][4];
#pragma unroll
  for (int mi = 0; mi < 4; ++mi)
#pragma unroll
    for (int ni = 0; ni < 4; ++ni) { acc0[mi][ni] = zero; acc1[mi][ni] = zero; }

  int r15 = lane & 15, kg = lane >> 4;
  int row0 = (wave >> 1) * 64, col0 = (wave & 1) * 64;
  int swz7 = r15 & 7;

  for (int kt = 0; kt < D_DIM / BK; ++kt) {
    size_t ko = (size_t)kt * BK;
#pragma unroll
    for (int j = 0; j < 4; ++j) {
      gl2lds16(gA[j] + ko,  smem + (tid + 256 * j) * 16);
      gl2lds16(gB0[j] + ko, smem + 16384 + (tid + 256 * j) * 16);
      gl2lds16(gB1[j] + ko, smem + 32768 + (tid + 256 * j) * 16);
    }
    __syncthreads();   // drains vmcnt+lgkmcnt
#pragma unroll
    for (int ks = 0; ks < 2; ++ks) {
      int ksw = ks << 2;
      bf16x8 bf0[4], bf1[4];
#pragma unroll
      for (int ni = 0; ni < 4; ++ni) {
        int rB = col0 + ni * 16 + r15;
        bf0[ni] = *(const bf16x8*)&sB0[rB * 64 + (((ksw | kg) ^ swz7) << 3)];
        bf1[ni] = *(const bf16x8*)&sB1[rB * 64 + (((ksw | kg) ^ swz7) << 3)];
      }
#pragma unroll
      for (int mi = 0; mi < 4; ++mi) {
        int rA = row0 + mi * 16 + r15;
        bf16x8 a = *(const bf16x8*)&sA[rA * 64 + (((ksw | kg) ^ swz7) << 3)];
#pragma unroll
        for (int ni = 0; ni < 4; ++ni) {
          acc0[mi][ni] = __builtin_amdgcn_mfma_f32_16x16x32_bf16(a, bf0[ni], acc0[mi][ni], 0, 0, 0);
          acc1[mi][ni] = __builtin_amdgcn_mfma_f32_16x16x32_bf16(a, bf1[ni], acc1[mi][ni], 0, 0, 0);
        }
      }
    }
    __syncthreads();
  }

  // epilogue: h = silu(s0)*s1 -> padded LDS transpose -> 16B stores
  int kg4 = kg * 4;
#pragma unroll
  for (int mi = 0; mi < 4; ++mi) {
#pragma unroll
    for (int ni = 0; ni < 4; ++ni) {
      f32x4 s0 = acc0[mi][ni], s1 = acc1[mi][ni];
#pragma unroll
      for (int j = 0; j < 4; ++j) {
        float v = s0[j];
        float h = v / (1.f + __expf(-v)) * s1[j];
        sH[(row0 + mi * 16 + kg4 + j) * SHP + col0 + ni * 16 + r15] = f2bf(h);
      }
    }
  }
  __syncthreads();
  {
    int r = tid >> 1;
    const unsigned short* sp = &sH[r * SHP + (tid & 1) * 64];
    unsigned short* hp = H + ((size_t)tileR * BM + r) * F_DIM + fc + (tid & 1) * 64;
#pragma unroll
    for (int cch = 0; cch < 8; ++cch)
      ((u32x4*)hp)[cch] = ((const u32x4*)sp)[cch];
  }
}

// ---------------- GEMM2: out[tok] += w * (H @ Wo) ----------------
// BK=64, same swizzle scheme. grid: (D/BN, MAXTILES)

__global__ __launch_bounds__(256, 2) void moe_gemm2_kernel(
    const unsigned short* __restrict__ H,
    const unsigned short* __restrict__ wot,   // [E][D][F] bf16
    const int* __restrict__ ctok,
    const float* __restrict__ cw,
    const int* __restrict__ texp,
    float* __restrict__ out) {
  int tileR = blockIdx.y;
  int e = texp[tileR];
  if (e < 0) return;
  int dc = blockIdx.x * BN;
  int tid = threadIdx.x, lane = tid & 63, wave = tid >> 6;

  __shared__ __align__(16) unsigned char smem[32768];  // A 16K | B 16K
  unsigned short* sA = (unsigned short*)(smem);
  unsigned short* sB = (unsigned short*)(smem + 16384);
  __shared__ int stok[BM];
  __shared__ float sw[BM];
  if (tid < BM) { stok[tid] = ctok[tileR * BM + tid]; sw[tid] = cw[tileR * BM + tid]; }

  const unsigned short* gA[4];
  const unsigned short* gB[4];
#pragma unroll
  for (int j = 0; j < 4; ++j) {
    int c = tid + 256 * j;
    int r = c >> 3;
    int lc = (c & 7) ^ (r & 7);
    gA[j] = H + ((size_t)tileR * BM + r) * F_DIM + lc * 8;
    gB[j] = wot + ((size_t)e * D_DIM + dc + r) * F_DIM + lc * 8;
  }

  f32x4 zero = {0.f, 0.f, 0.f, 0.f};
  f32x4 acc[4][4];
#pragma unroll
  for (int mi = 0; mi < 4; ++mi)
#pragma unroll
    for (int ni = 0; ni < 4; ++ni) acc[mi][ni] = zero;

  int r15 = lane & 15, kg = lane >> 4, kg4 = kg * 4;
  int row0 = (wave >> 1) * 64, col0 = (wave & 1) * 64;
  int swz7 = r15 & 7;

  for (int kt = 0; kt < F_DIM / BK; ++kt) {
    size_t ko = (size_t)kt * BK;
#pragma unroll
    for (int j = 0; j < 4; ++j) {
      gl2lds16(gA[j] + ko, smem + (tid + 256 * j) * 16);
      gl2lds16(gB[j] + ko, smem + 16384 + (tid + 256 * j) * 16);
    }
    __syncthreads();
#pragma unroll
    for (int ks = 0; ks < 2; ++ks) {
      int ksw = ks << 2;
      bf16x8 bfr[4];
#pragma unroll
      for (int ni = 0; ni < 4; ++ni) {
        int rB = col0 + ni * 16 + r15;
        bfr[ni] = *(const bf16x8*)&sB[rB * 64 + (((ksw | kg) ^ swz7) << 3)];
      }
#pragma unroll
      for (int mi = 0; mi < 4; ++mi) {
        int rA = row0 + mi * 16 + r15;
        bf16x8 a = *(const bf16x8*)&sA[rA * 64 + (((ksw | kg) ^ swz7) << 3)];
#pragma unroll
        for (int ni = 0; ni < 4; ++ni)
          acc[mi][ni] = __builtin_amdgcn_mfma_f32_16x16x32_bf16(a, bfr[ni], acc[mi][ni], 0, 0, 0);
      }
    }
    __syncthreads();
  }

#pragma unroll
  for (int mi = 0; mi < 4; ++mi) {
#pragma unroll
    for (int ni = 0; ni < 4; ++ni) {
#pragma unroll
      for (int j = 0; j < 4; ++j) {
        int r = row0 + mi * 16 + kg4 + j;
        int tok = stok[r];
        if (tok >= 0) {
          float val = acc[mi][ni][j] * sw[r];
          atomicAdd(&out[(size_t)tok * D_DIM + dc + col0 + ni * 16 + r15], val);
        }
      }
    }
  }
}

// ---------------- launch ----------------

extern "C" void kernel_launch(void* const* d_in, const int* in_sizes, int n_in,
                              void* d_out, int out_size, void* d_ws, size_t ws_size,
                              hipStream_t stream) {
  const float* x  = (const float*)d_in[0];
  const float* wg = (const float*)d_in[1];
  const float* w0 = (const float*)d_in[2];
  const float* w1 = (const float*)d_in[3];
  const float* wo = (const float*)d_in[4];
  float* out = (float*)d_out;

  char* ws = (char*)d_ws;
  size_t o = 0;
  auto carve = [&](size_t bytes) {
    char* p = ws + o;
    o = (o + bytes + 255) & ~(size_t)255;
    return p;
  };
  unsigned short* xbf  = (unsigned short*)carve((size_t)T_TOK * D_DIM * 2);         // 16 MB
  unsigned short* w0t  = (unsigned short*)carve((size_t)E_NUM * F_DIM * D_DIM * 2); // 64 MB
  unsigned short* w1t  = (unsigned short*)carve((size_t)E_NUM * F_DIM * D_DIM * 2); // 64 MB
  unsigned short* Hbuf = (unsigned short*)carve((size_t)MAXROWS * F_DIM * 2);       // 136 MB
  int*   counts = (int*)carve(8 * 4);
  int*   btok   = (int*)carve((size_t)E_NUM * T_TOK * 4);
  float* bwts   = (float*)carve((size_t)E_NUM * T_TOK * 4);
  int*   ctok   = (int*)carve((size_t)MAXROWS * 4);
  float* cwts   = (float*)carve((size_t)MAXROWS * 4);
  int*   texp   = (int*)carve((size_t)MAXTILES * 4);
  unsigned short* wot = w0t;   // aliased; wo transpose runs after gemm1
  (void)ws_size; (void)in_sizes; (void)n_in; (void)out_size;

  (void)hipMemsetAsync(d_out, 0, (size_t)T_TOK * D_DIM * 4, stream);
  (void)hipMemsetAsync(counts, 0, 8 * 4, stream);

  cvt_x_kernel<<<T_TOK * D_DIM / 4 / 256, 256, 0, stream>>>(x, xbf);
  transpose_cast_kernel<<<dim3(F_DIM / 64, D_DIM / 128, E_NUM), 256, 0, stream>>>(w0, w0t, D_DIM, F_DIM);
  transpose_cast_kernel<<<dim3(F_DIM / 64, D_DIM / 128, E_NUM), 256, 0, stream>>>(w1, w1t, D_DIM, F_DIM);
  gate_kernel<<<T_TOK / 4, 256, 0, stream>>>(x, wg, counts, btok, bwts);
  route_kernel<<<1, 256, 0, stream>>>(counts, btok, bwts, ctok, cwts, texp);
  moe_gemm1_kernel<<<dim3(F_DIM / BN, MAXTILES), 256, 0, stream>>>(xbf, w0t, w1t, ctok, texp, Hbuf);
  transpose_cast_kernel<<<dim3(D_DIM / 64, F_DIM / 128, E_NUM), 256, 0, stream>>>(wo, wot, F_DIM, D_DIM);
  moe_gemm2_kernel<<<dim3(D_DIM / BN, MAXTILES), 256, 0, stream>>>(Hbuf, wot, ctok, cwts, texp, out);
}